// Round 5
// baseline (939.725 us; speedup 1.0000x reference)
//
#include <hip/hip_runtime.h>
#include <math.h>

// ---------------------------------------------------------------------------
// PiT: encoder lift -> down pos-att -> 4x (pos-att + MLP + residual) -> up
// pos-att -> decoder. Sparse attention via exact percentile selection
// (histogram/counting-based order statistics), fused with the PV gather.
// ---------------------------------------------------------------------------

__device__ __forceinline__ float gelu_f(float x) {
  float x3 = x * x * x;
  float inner = x + 0.044715f * x3;
  float t = tanhf(0.7978845608028654f * inner);
  return x * (0.5f * (1.0f + t));
}

// ---------------- encoder lift: out[m][o] = gelu(x[m]·w[o] + b[o]), K=3 -----
__global__ __launch_bounds__(256) void k_lift(const float* __restrict__ x,
                                              const float* __restrict__ w,
                                              const float* __restrict__ b,
                                              float* __restrict__ out) {
  int gid = blockIdx.x * 256 + threadIdx.x;
  int m = gid >> 8, o = gid & 255;
  float a0 = x[m * 3 + 0], a1 = x[m * 3 + 1], a2 = x[m * 3 + 2];
  float acc = a0 * w[o * 3 + 0] + a1 * w[o * 3 + 1] + a2 * w[o * 3 + 2] + b[o];
  out[gid] = gelu_f(acc);
}

// ---------------- dense linear: C = act(A @ W^T + bias [+ D]) ---------------
template <int WL, int ACT, int ADDRES>
__global__ __launch_bounds__(256) void k_linear(const float* __restrict__ A,
                                                const float* __restrict__ W,
                                                const float* __restrict__ bias,
                                                const float* __restrict__ D,
                                                float* __restrict__ C, int M) {
  __shared__ __align__(16) float Al[32][68];
  __shared__ __align__(16) float Wl[32][68];
  int t = threadIdx.x;
  int m0 = blockIdx.x * 64, o0 = blockIdx.y * 64;
  int tr = t >> 4, tc = t & 15;
  float acc[4][4] = {{0.0f}};
  for (int kb = 0; kb < 256; kb += 32) {
#pragma unroll
    for (int e = 0; e < 2; ++e) {
      int idx = t + 256 * e;
      int m = idx >> 3;
      int kq = idx & 7;
      float4 v = *(const float4*)(A + (size_t)(m0 + m) * 256 + kb + kq * 4);
      Al[kq * 4 + 0][m] = v.x; Al[kq * 4 + 1][m] = v.y;
      Al[kq * 4 + 2][m] = v.z; Al[kq * 4 + 3][m] = v.w;
    }
    if (WL == 0) {
#pragma unroll
      for (int e = 0; e < 2; ++e) {
        int idx = t + 256 * e;
        int o = idx >> 3;
        int kq = idx & 7;
        float4 v = *(const float4*)(W + (size_t)(o0 + o) * 256 + kb + kq * 4);
        Wl[kq * 4 + 0][o] = v.x; Wl[kq * 4 + 1][o] = v.y;
        Wl[kq * 4 + 2][o] = v.z; Wl[kq * 4 + 3][o] = v.w;
      }
    } else {
#pragma unroll
      for (int e = 0; e < 8; ++e) {
        int idx = t + 256 * e;
        int k = idx >> 6, o = idx & 63;
        int cc = o0 + o;
        Wl[k][o] = W[(size_t)(cc >> 5) * 8192 + (size_t)(kb + k) * 32 + (cc & 31)];
      }
    }
    __syncthreads();
#pragma unroll
    for (int kk = 0; kk < 32; ++kk) {
      float4 av = *(const float4*)&Al[kk][tr * 4];
      float4 wv = *(const float4*)&Wl[kk][tc * 4];
      float aa[4] = {av.x, av.y, av.z, av.w};
      float ww[4] = {wv.x, wv.y, wv.z, wv.w};
#pragma unroll
      for (int i = 0; i < 4; i++)
#pragma unroll
        for (int jx = 0; jx < 4; jx++)
          acc[i][jx] = fmaf(aa[i], ww[jx], acc[i][jx]);
    }
    __syncthreads();
  }
#pragma unroll
  for (int i = 0; i < 4; i++) {
    int m = m0 + tr * 4 + i;
#pragma unroll
    for (int jx = 0; jx < 4; jx++) {
      int o = o0 + tc * 4 + jx;
      float v = acc[i][jx];
      if (bias) v += bias[o];
      if (ADDRES) v += D[(size_t)m * 256 + o];
      if (ACT) v = gelu_f(v);
      C[(size_t)m * 256 + o] = v;
    }
  }
}

// ---------------- precompute the 48 attention scales ------------------------
__global__ void k_scales(const float* __restrict__ down_r,
                         const float* __restrict__ pa_r,
                         const float* __restrict__ up_r,
                         float* __restrict__ scales) {
  int t = threadIdx.x;
  if (t >= 48) return;
  float rv;
  if (t < 8) rv = down_r[t];
  else if (t < 40) rv = pa_r[t - 8];
  else rv = up_r[t - 40];
  double rd = (double)rv;
  float s1 = (float)sin(rd);
  float u = 1.0f + s1;
  float vc = (float)(0.7853981633974483 * (1.0 - 1e-7));
  float wf = vc * u;
  scales[t] = (float)tan((double)wf);
}

// ---------------- fused percentile selection + softmax + PV gather ----------
// Per block = one (h, q-row): find thr (histogram + counting selection in the
// raw domain; thresholds on f32-rounded products = reference-exact), compact
// the kept set into LDS, normalize softmax weights on the K-sized list, then
// gather-accumulate V and write gelu(out) directly.
template <int N>
__global__ __launch_bounds__(256) void k_selpv(
    const float* __restrict__ mdist, const float* __restrict__ scales,
    int sc_off, int Nq, int k_lo, float hw, float lw,
    const float* __restrict__ V, int Nk, float* __restrict__ out) {
  constexpr int NPT = N / 256;
  constexpr int KCAP = 192;
  __shared__ __align__(16) float srow[N];
  __shared__ int hist[256];
  __shared__ float sredf[8];
  __shared__ int swoff[4];
  __shared__ int sbinlo, sbinhi, sibase, sincl, sgc;
  __shared__ float scand[128];
  __shared__ float svsel[2];
  __shared__ int kil[KCAP];
  __shared__ float kvw[KCAP];
  __shared__ float pacc[128];

  int row = blockIdx.x;
  int t = threadIdx.x;
  int wid = t >> 6, lane = t & 63;
  int h = row / Nq, j = row - h * Nq;
  float scale = scales[sc_off + h];
  const float* mrow = mdist + (size_t)row * N;

  // ---- load row into LDS (float4), track min/max ----
  float lmin = INFINITY, lmax = -INFINITY;
#pragma unroll
  for (int e = 0; e < NPT / 4; ++e) {
    int i4 = t + 256 * e;
    float4 v = ((const float4*)mrow)[i4];
    ((float4*)srow)[i4] = v;
    lmin = fminf(lmin, fminf(fminf(v.x, v.y), fminf(v.z, v.w)));
    lmax = fmaxf(lmax, fmaxf(fmaxf(v.x, v.y), fmaxf(v.z, v.w)));
  }
#pragma unroll
  for (int off = 32; off > 0; off >>= 1) {
    lmin = fminf(lmin, __shfl_xor(lmin, off));
    lmax = fmaxf(lmax, __shfl_xor(lmax, off));
  }
  if (lane == 0) { sredf[wid] = lmin; sredf[4 + wid] = lmax; }
  __syncthreads();
  float rmin = fminf(fminf(sredf[0], sredf[1]), fminf(sredf[2], sredf[3]));
  float rmax = fmaxf(fmaxf(sredf[4], sredf[5]), fmaxf(sredf[6], sredf[7]));

  float rlo = rmin;
  float rhi = rmax + fmaxf(fabsf(rmax) * 1e-6f, 1e-30f);
  float v_lo = rmin, v_hi = rmin;  // fallback for degenerate rows

  for (int it = 0; it < 8; ++it) {
    // rank of rlo (skip on iter 0: rlo == rmin => nothing strictly below)
    if (it > 0) {
      int lb = 0;
#pragma unroll
      for (int e = 0; e < NPT; ++e) lb += (srow[t + 256 * e] < rlo) ? 1 : 0;
#pragma unroll
      for (int off = 32; off > 0; off >>= 1) lb += __shfl_xor(lb, off);
      if (lane == 0) swoff[wid] = lb;
    }
    hist[t] = 0;
    __syncthreads();
    int below = (it > 0) ? (swoff[0] + swoff[1] + swoff[2] + swoff[3]) : 0;
    int r = k_lo - below;  // rank within [rlo, rhi)
    float width = rhi - rlo;
    float sinv = 256.0f / width;
#pragma unroll
    for (int e = 0; e < NPT; ++e) {
      float v = srow[t + 256 * e];
      if (v >= rlo && v < rhi) {
        int b = (int)((v - rlo) * sinv);
        b = b < 0 ? 0 : (b > 255 ? 255 : b);
        atomicAdd(&hist[b], 1);
      }
    }
    __syncthreads();
    // exclusive scan of 256-bin histogram
    int c = hist[t];
    int x = c;
#pragma unroll
    for (int off = 1; off < 64; off <<= 1) {
      int y = __shfl_up(x, off);
      if (lane >= off) x += y;
    }
    if (lane == 63) swoff[wid] = x;
    __syncthreads();
    int wo = 0;
#pragma unroll
    for (int w = 0; w < 4; ++w) wo += (w < wid) ? swoff[w] : 0;
    int incl = x + wo;
    int excl = incl - c;
    if (excl <= r && r < incl) { sbinlo = t; sibase = excl; }
    if (excl <= r + 1 && r + 1 < incl) { sbinhi = t; sincl = incl; }
    if (t == 0) sgc = 0;
    __syncthreads();
    int b_lo = sbinlo, b_hi = sbinhi;
    int base = sibase;
    int gcount = sincl - base;
    if (gcount <= 128) {
      // gather candidate values; order-free counting selection below
#pragma unroll
      for (int e = 0; e < NPT; ++e) {
        float v = srow[t + 256 * e];
        if (v >= rlo && v < rhi) {
          int b = (int)((v - rlo) * sinv);
          b = b < 0 ? 0 : (b > 255 ? 255 : b);
          if (b >= b_lo && b <= b_hi) {
            int p = atomicAdd(&sgc, 1);
            if (p < 128) scand[p] = v;
          }
        }
      }
      __syncthreads();
      int rr = r - base;
      if (t < gcount) {
        float xv = scand[t];
        int clt = 0, ceq = 0;
        for (int jj = 0; jj < gcount; ++jj) {
          float y = scand[jj];
          clt += (y < xv) ? 1 : 0;
          ceq += (y == xv) ? 1 : 0;
        }
        if (clt <= rr && rr < clt + ceq) svsel[0] = xv;
        if (clt <= rr + 1 && rr + 1 < clt + ceq) svsel[1] = xv;
      }
      __syncthreads();
      v_lo = svsel[0];
      v_hi = svsel[1];
      break;
    }
    // refine range conservatively
    float w256 = width * (1.0f / 256.0f);
    float nlo = rlo + ((float)b_lo - 0.5f) * w256;
    float nhi = rlo + ((float)b_hi + 1.5f) * w256;
    rlo = fmaxf(rlo, nlo);
    rhi = fminf(rhi, nhi);
    __syncthreads();
  }

  // ---- threshold on rounded products (reference-exact formula) ----
  float vlos = __fmul_rn(v_lo, scale);
  float vhis = __fmul_rn(v_hi, scale);
  float thr = __fadd_rn(__fmul_rn(vlos, lw), __fmul_rn(vhis, hw));
  float rmins = __fmul_rn(rmin, scale);

  // ---- compact kept set into LDS (deterministic thread-major order) ----
  int myc = 0;
#pragma unroll
  for (int e = 0; e < NPT; ++e) {
    float sdv = __fmul_rn(srow[t + 256 * e], scale);
    myc += (sdv <= thr) ? 1 : 0;
  }
  int xs = myc;
#pragma unroll
  for (int off = 1; off < 64; off <<= 1) {
    int y = __shfl_up(xs, off);
    if (lane >= off) xs += y;
  }
  if (lane == 63) swoff[wid] = xs;
  __syncthreads();
  int wo2 = 0;
#pragma unroll
  for (int w = 0; w < 4; ++w) wo2 += (w < wid) ? swoff[w] : 0;
  int p = wo2 + xs - myc;
  int K = swoff[0] + swoff[1] + swoff[2] + swoff[3];
  if (K > KCAP) K = KCAP;
#pragma unroll
  for (int e = 0; e < NPT; ++e) {
    int i = t + 256 * e;
    float m = srow[i];
    if (__fmul_rn(m, scale) <= thr) {
      if (p < KCAP) { kil[p] = i; kvw[p] = m; }
      p++;
    }
  }
  __syncthreads();

  // ---- softmax weights on the K-sized compact list ----
  float e0 = 0.0f;
  if (t < K) {
    float sdv = __fmul_rn(kvw[t], scale);
    e0 = expf(__fsub_rn(rmins, sdv));
  }
  float es = e0;
#pragma unroll
  for (int off = 32; off > 0; off >>= 1) es += __shfl_xor(es, off);
  if (lane == 0) sredf[wid] = es;
  __syncthreads();
  float total = (sredf[0] + sredf[1]) + (sredf[2] + sredf[3]);
  if (t < K) kvw[t] = e0 / total;
  __syncthreads();

  // ---- PV gather: out[b][j][h*32+c] = gelu(sum_e w_e * V[b][n_e][h*32+c]) ---
  int half = t >> 7, b = (t >> 5) & 3, c = t & 31;
  int hcol = h * 32 + c;
  float acc = 0.0f;
  for (int e = half; e < K; e += 2)
    acc = fmaf(kvw[e], V[((size_t)b * Nk + kil[e]) * 256 + hcol], acc);
  if (half) pacc[t - 128] = acc;
  __syncthreads();
  if (!half) {
    float r2 = acc + pacc[t];
    out[((size_t)b * Nq + j) * 256 + hcol] = gelu_f(r2);
  }
}

// ---------------- final 256->1 projection -----------------------------------
__global__ __launch_bounds__(256) void k_de2(const float* __restrict__ A,
                                             const float* __restrict__ w,
                                             const float* __restrict__ b,
                                             float* __restrict__ out) {
  int t = threadIdx.x;
  int row = blockIdx.x * 4 + (t >> 6);
  int lane = t & 63;
  const float* ar = A + (size_t)row * 256;
  float s = 0.0f;
  for (int i = lane; i < 256; i += 64) s = fmaf(ar[i], w[i], s);
#pragma unroll
  for (int off = 32; off > 0; off >>= 1) s += __shfl_down(s, off);
  if (lane == 0) out[row] = s + b[0];
}

// ---------------------------------------------------------------------------
struct SelParams { int k_lo; float hw, lw; };
static SelParams sel_params(double q, int N) {
  SelParams p;
  float idx_q = (float)(q / 100.0);
  float pos = idx_q * (float)(N - 1);
  float lo = floorf(pos);
  p.k_lo = (int)lo;
  p.hw = pos - lo;
  p.lw = 1.0f - p.hw;
  return p;
}

extern "C" void kernel_launch(void* const* d_in, const int* in_sizes, int n_in,
                              void* d_out, int out_size, void* d_ws, size_t ws_size,
                              hipStream_t stream) {
  const float* x      = (const float*)d_in[0];
  const float* mdd    = (const float*)d_in[1];
  const float* mdb    = (const float*)d_in[2];
  const float* mdu    = (const float*)d_in[3];
  const float* en_w   = (const float*)d_in[4];
  const float* en_b   = (const float*)d_in[5];
  const float* down_r = (const float*)d_in[6];
  const float* down_w = (const float*)d_in[7];
  const float* pa_r   = (const float*)d_in[8];
  const float* pa_w   = (const float*)d_in[9];
  const float* mlp1_w = (const float*)d_in[10];
  const float* mlp1_b = (const float*)d_in[11];
  const float* mlp2_w = (const float*)d_in[12];
  const float* mlp2_b = (const float*)d_in[13];
  const float* res_w  = (const float*)d_in[14];
  const float* res_b  = (const float*)d_in[15];
  const float* up_r   = (const float*)d_in[16];
  const float* up_w   = (const float*)d_in[17];
  const float* de1_w  = (const float*)d_in[18];
  const float* de1_b  = (const float*)d_in[19];
  const float* de2_w  = (const float*)d_in[20];
  const float* de2_b  = (const float*)d_in[21];
  float* out = (float*)d_out;
  float* ws = (float*)d_ws;

  // ws layout (floats)
  float* hfull = ws;                     // 4194304
  float* val   = ws + 4194304;           // 4194304
  float* paout = ws + 8388608;           // 4194304
  float* hlat  = ws + 12582912;          // 1048576
  float* t1    = ws + 13631488;          // 1048576
  float* t2    = ws + 14680064;          // 1048576
  float* scales = ws + 15728640;         // 48

  k_scales<<<1, 64, 0, stream>>>(down_r, pa_r, up_r, scales);

  // encoder
  k_lift<<<16384, 256, 0, stream>>>(x, en_w, en_b, hfull);

  // down stage (H=8, Nq=1024, Nk=4096, q=3 -> keep ~123)
  SelParams pd = sel_params(3.0, 4096);
  k_linear<1, 0, 0><<<dim3(256, 4), 256, 0, stream>>>(hfull, down_w, nullptr, nullptr, val, 16384);
  k_selpv<4096><<<8192, 256, 0, stream>>>(mdd, scales, 0, 1024, pd.k_lo, pd.hw, pd.lw, val, 4096, hlat);

  // processor blocks (Nq=Nk=1024, q=5 -> keep ~52)
  SelParams pb = sel_params(5.0, 1024);
  for (int i = 0; i < 4; i++) {
    k_linear<1, 0, 0><<<dim3(64, 4), 256, 0, stream>>>(hlat, pa_w + (size_t)i * 65536, nullptr, nullptr, val, 4096);
    k_selpv<1024><<<8192, 256, 0, stream>>>(mdb + (size_t)i * 8388608, scales, 8 + i * 8, 1024, pb.k_lo, pb.hw, pb.lw, val, 1024, paout);
    k_linear<0, 1, 0><<<dim3(64, 4), 256, 0, stream>>>(paout, mlp1_w + (size_t)i * 65536, mlp1_b + i * 256, nullptr, t1, 4096);
    k_linear<0, 0, 0><<<dim3(64, 4), 256, 0, stream>>>(hlat, res_w + (size_t)i * 65536, res_b + i * 256, nullptr, t2, 4096);
    k_linear<0, 1, 1><<<dim3(64, 4), 256, 0, stream>>>(t1, mlp2_w + (size_t)i * 65536, mlp2_b + i * 256, t2, hlat, 4096);
  }

  // up stage (H=8, Nq=4096, Nk=1024, q=3 -> keep ~31)
  SelParams pu = sel_params(3.0, 1024);
  k_linear<1, 0, 0><<<dim3(64, 4), 256, 0, stream>>>(hlat, up_w, nullptr, nullptr, val, 4096);
  k_selpv<1024><<<32768, 256, 0, stream>>>(mdu, scales, 40, 4096, pu.k_lo, pu.hw, pu.lw, val, 1024, paout);

  // decoder
  k_linear<0, 1, 0><<<dim3(256, 4), 256, 0, stream>>>(paout, de1_w, de1_b, nullptr, hfull, 16384);
  k_de2<<<4096, 256, 0, stream>>>(hfull, de2_w, de2_b, out);
}